// Round 7
// baseline (369.144 us; speedup 1.0000x reference)
//
#include <hip/hip_runtime.h>

// Transformer block, B=2 T=2048 D=1024 H=16 HS=64, bf16 MFMA pipeline.
// R7: R5 core (BK=64 twin panels, 2 barriers / 64-K) + 32x32x16 MFMA
//     (half the MFMA issue slots per FLOP) + k-column rotation by 8*(row&3)
//     (keeps 32-row fragment reads at 8-way aliasing; rotation folded into
//     staging source cols and reader pointers - zero inner-loop cost).

typedef __bf16 bf16;
typedef __attribute__((ext_vector_type(8)))  __bf16 bf16x8;
typedef __attribute__((ext_vector_type(4)))  __bf16 bf16x4;
typedef __attribute__((ext_vector_type(4)))  short  shortx4;
typedef __attribute__((ext_vector_type(4)))  float  floatx4;
typedef __attribute__((ext_vector_type(16))) float  floatx16;

__device__ __forceinline__ short f2bf_bits(float x) {
  return __builtin_bit_cast(short, (bf16)x);
}

// async global->LDS, 16B per lane. LDS dest is wave-uniform base + lane*16.
__device__ __forceinline__ void gl2lds16(const bf16* g, bf16* l) {
  __builtin_amdgcn_global_load_lds((const __attribute__((address_space(1))) void*)g,
                                   (__attribute__((address_space(3))) void*)l, 16, 0, 0);
}

// ---------------- prep: weight transpose+cvt (ids 0..12287) + LN1 (ids 12288+) ----
__global__ __launch_bounds__(256) void prep_kernel(
    const float* __restrict__ Wq, const float* __restrict__ Wk,
    const float* __restrict__ Wv, const float* __restrict__ Wo,
    const float* __restrict__ W1, const float* __restrict__ W2,
    bf16* __restrict__ WqkvT, bf16* __restrict__ WoT,
    bf16* __restrict__ W1T, bf16* __restrict__ W2T,
    const float* __restrict__ x, const float* __restrict__ ln1g,
    const float* __restrict__ ln1b, bf16* __restrict__ h1)
{
  int id = blockIdx.x;
  if (id >= 12288) {   // ---- LN1 row ----
    const int row = id - 12288, t = threadIdx.x;
    const float* xr = x + (size_t)row * 1024;
    float4 v = *(const float4*)(xr + t * 4);
    float s  = v.x + v.y + v.z + v.w;
    float s2 = v.x * v.x + v.y * v.y + v.z * v.z + v.w * v.w;
    #pragma unroll
    for (int off = 1; off < 64; off <<= 1) {
      s  += __shfl_xor(s, off);
      s2 += __shfl_xor(s2, off);
    }
    __shared__ float ps[4], ps2[4];
    int wv = t >> 6;
    if ((t & 63) == 0) { ps[wv] = s; ps2[wv] = s2; }
    __syncthreads();
    s  = ps[0] + ps[1] + ps[2] + ps[3];
    s2 = ps2[0] + ps2[1] + ps2[2] + ps2[3];
    const float mu = s * (1.0f / 1024.0f);
    const float rstd = rsqrtf(s2 * (1.0f / 1024.0f) - mu * mu + 1e-5f);
    float4 gv = *(const float4*)(ln1g + t * 4);
    float4 bv = *(const float4*)(ln1b + t * 4);
    bf16x4 o;
    o[0] = (bf16)((v.x - mu) * rstd * gv.x + bv.x);
    o[1] = (bf16)((v.y - mu) * rstd * gv.y + bv.y);
    o[2] = (bf16)((v.z - mu) * rstd * gv.z + bv.z);
    o[3] = (bf16)((v.w - mu) * rstd * gv.w + bv.w);
    *(bf16x4*)(h1 + (size_t)row * 1024 + t * 4) = o;
    return;
  }
  // ---- weight transpose tile ----
  const float* src; bf16* dst; int K, N, tile;
  if (id < 4096) {
    K = 1024; N = 1024; tile = id & 1023;
    int wsel = id >> 10;
    src = (wsel == 0) ? Wq : (wsel == 1) ? Wk : (wsel == 2) ? Wv : Wo;
    dst = (wsel < 3) ? (WqkvT + (size_t)wsel * 1024 * 1024) : WoT;
  } else if (id < 8192) {
    K = 1024; N = 4096; tile = id - 4096; src = W1; dst = W1T;
  } else {
    K = 4096; N = 1024; tile = id - 8192; src = W2; dst = W2T;
  }
  int ntn = N >> 5;
  int k0 = (tile / ntn) * 32, n0 = (tile % ntn) * 32;
  __shared__ float tl[32][33];
  int tr = threadIdx.x >> 3, tc = (threadIdx.x & 7) * 4;
  float4 v = *(const float4*)(src + (size_t)(k0 + tr) * N + n0 + tc);
  tl[tr][tc + 0] = v.x; tl[tr][tc + 1] = v.y; tl[tr][tc + 2] = v.z; tl[tr][tc + 3] = v.w;
  __syncthreads();
  bf16x4 o = { (bf16)tl[tc + 0][tr], (bf16)tl[tc + 1][tr],
               (bf16)tl[tc + 2][tr], (bf16)tl[tc + 3][tr] };
  *(bf16x4*)(dst + (size_t)(n0 + tr) * K + k0 + tc) = o;
}

// ---------------- shared GEMM core: BK=64 twin panels, 32x32x16 MFMA -------------
// LDS panel layout: row r (0..127) x 32 k, stride 32, with k-cols of row r
// rotated left by 8*(r&3) (applied on the staging SOURCE column; LDS dest
// stays lane-contiguous as global_load_lds requires).
// acc[rb][cb] = C^T fragment of the 32x32 block: C-row m = lane&31,
// C-col n = 8*(reg>>2) + 4*(lane>>5) + (reg&3).
__device__ __forceinline__ void gemm_core(
    const bf16* __restrict__ A, const bf16* __restrict__ Bt,
    int Ktot, int k0, int k1, bf16* As, bf16* Bs, floatx16 (&acc)[2][2])
{
  const int tid = threadIdx.x, lane = tid & 63, wv = tid >> 6;
  const int r = lane & 31, hi = lane >> 5;
  const int wm = wv >> 1, wn = wv & 1;
  const int srow = wv * 16 + (lane >> 2);
  const int scol = (((lane & 3) + (srow & 3)) & 3) * 8;   // rotated source col
  const bf16* aP = A  + (size_t)srow * Ktot + scol;
  const bf16* bP = Bt + (size_t)srow * Ktot + scol;
  bf16* AsW = As + wv * 512;
  bf16* BsW = Bs + wv * 512;
  // reader cols within a 32-panel (inverse rotation), per k-half
  const int cc0 = ((0 + hi * 8 - (r & 3) * 8) & 31);
  const int cc1 = ((16 + hi * 8 - (r & 3) * 8) & 31);
  const bf16* a0P = As + (wm * 64 + r) * 32;
  const bf16* a1P = As + (wm * 64 + 32 + r) * 32;
  const bf16* b0P = Bs + (wn * 64 + r) * 32;
  const bf16* b1P = Bs + (wn * 64 + 32 + r) * 32;
  for (int kt = k0; kt < k1; kt += 64) {
    gl2lds16(aP + kt,                          AsW);
    gl2lds16(aP + kt + (size_t)64 * Ktot,      AsW + 2048);
    gl2lds16(aP + kt + 32,                     AsW + 4096);
    gl2lds16(aP + kt + 32 + (size_t)64 * Ktot, AsW + 6144);
    gl2lds16(bP + kt,                          BsW);
    gl2lds16(bP + kt + (size_t)64 * Ktot,      BsW + 2048);
    gl2lds16(bP + kt + 32,                     BsW + 4096);
    gl2lds16(bP + kt + 32 + (size_t)64 * Ktot, BsW + 6144);
    __syncthreads();
    #pragma unroll
    for (int h = 0; h < 2; ++h) {
      const int pb = h * 4096;
      #pragma unroll
      for (int kh = 0; kh < 2; ++kh) {
        const int cc = kh ? cc1 : cc0;
        bf16x8 a0 = *(const bf16x8*)(a0P + pb + cc);
        bf16x8 a1 = *(const bf16x8*)(a1P + pb + cc);
        bf16x8 b0 = *(const bf16x8*)(b0P + pb + cc);
        bf16x8 b1 = *(const bf16x8*)(b1P + pb + cc);
        acc[0][0] = __builtin_amdgcn_mfma_f32_32x32x16_bf16(b0, a0, acc[0][0], 0, 0, 0);
        acc[0][1] = __builtin_amdgcn_mfma_f32_32x32x16_bf16(b1, a0, acc[0][1], 0, 0, 0);
        acc[1][0] = __builtin_amdgcn_mfma_f32_32x32x16_bf16(b0, a1, acc[1][0], 0, 0, 0);
        acc[1][1] = __builtin_amdgcn_mfma_f32_32x32x16_bf16(b1, a1, acc[1][1], 0, 0, 0);
      }
    }
    __syncthreads();
  }
}

// ---------------- GEMM: C[M,N] = A[M,K] @ Bt[N,K]^T ----------------
template<bool BIAS, bool RELU, bool RESID>
__global__ __launch_bounds__(256) void gemm_kernel(
    const bf16* __restrict__ A, const bf16* __restrict__ Bt,
    const float* __restrict__ bias, const float* __restrict__ resid,
    bf16* __restrict__ Cb, float* __restrict__ Cf,
    int M, int N, int K)
{
  __shared__ bf16 As[8192];
  __shared__ bf16 Bs[8192];
  const int lane = threadIdx.x & 63, wv = threadIdx.x >> 6;
  const int r = lane & 31, hi = lane >> 5;
  const int m0 = blockIdx.x * 128, n0 = blockIdx.y * 128;
  const int wm = wv >> 1, wn = wv & 1;
  floatx16 acc[2][2] = {};
  gemm_core(A + (size_t)m0 * K, Bt + (size_t)n0 * K, K, 0, K, As, Bs, acc);
  #pragma unroll
  for (int rb = 0; rb < 2; ++rb) {
    int m = m0 + wm * 64 + rb * 32 + r;
    #pragma unroll
    for (int cb = 0; cb < 2; ++cb) {
      int nb = n0 + wn * 64 + cb * 32 + hi * 4;
      #pragma unroll
      for (int rg = 0; rg < 4; ++rg) {
        int n = nb + rg * 8;
        float4 bv = BIAS ? *(const float4*)(bias + n) : float4{0, 0, 0, 0};
        float v0 = acc[rb][cb][rg * 4 + 0] + bv.x;
        float v1 = acc[rb][cb][rg * 4 + 1] + bv.y;
        float v2 = acc[rb][cb][rg * 4 + 2] + bv.z;
        float v3 = acc[rb][cb][rg * 4 + 3] + bv.w;
        if (RELU) {
          v0 = fmaxf(v0, 0.f); v1 = fmaxf(v1, 0.f);
          v2 = fmaxf(v2, 0.f); v3 = fmaxf(v3, 0.f);
        }
        size_t idx = (size_t)m * N + n;
        if (RESID) {
          float4 rv = *(const float4*)(resid + idx);
          float4 ov = { v0 + rv.x, v1 + rv.y, v2 + rv.z, v3 + rv.w };
          *(float4*)(Cf + idx) = ov;
        } else {
          bf16x4 ov = { (bf16)v0, (bf16)v1, (bf16)v2, (bf16)v3 };
          *(bf16x4*)(Cb + idx) = ov;
        }
      }
    }
  }
}

// ---------------- QKV GEMM: Q,K -> qkv row-major; V -> VtG[b*16+h][d][key] ----------
__global__ __launch_bounds__(256) void gemm_qkv(
    const bf16* __restrict__ A, const bf16* __restrict__ Bt,
    bf16* __restrict__ qkv, bf16* __restrict__ VtG)
{
  const int K = 1024;
  __shared__ bf16 As[8192];
  __shared__ bf16 Bs[8192];
  const int lane = threadIdx.x & 63, wv = threadIdx.x >> 6;
  const int r = lane & 31, hi = lane >> 5;
  const int m0 = blockIdx.x * 128, n0 = blockIdx.y * 128;
  const int wm = wv >> 1, wn = wv & 1;
  floatx16 acc[2][2] = {};
  gemm_core(A + (size_t)m0 * K, Bt + (size_t)n0 * K, K, 0, K, As, Bs, acc);
  if (n0 < 2048) {   // Q,K block: row-major vector stores into qkv
    #pragma unroll
    for (int rb = 0; rb < 2; ++rb) {
      int m = m0 + wm * 64 + rb * 32 + r;
      #pragma unroll
      for (int cb = 0; cb < 2; ++cb) {
        int nb = n0 + wn * 64 + cb * 32 + hi * 4;
        #pragma unroll
        for (int rg = 0; rg < 4; ++rg) {
          int n = nb + rg * 8;
          bf16x4 ov = { (bf16)acc[rb][cb][rg * 4 + 0], (bf16)acc[rb][cb][rg * 4 + 1],
                        (bf16)acc[rb][cb][rg * 4 + 2], (bf16)acc[rb][cb][rg * 4 + 3] };
          *(bf16x4*)(qkv + (size_t)m * 3072 + n) = ov;
        }
      }
    }
  } else {           // V block: scatter transposed into VtG (lanes walk keys)
    #pragma unroll
    for (int rb = 0; rb < 2; ++rb) {
      int m = m0 + wm * 64 + rb * 32 + r;
      int key = m & 2047, bq = m >> 11;
      #pragma unroll
      for (int cb = 0; cb < 2; ++cb) {
        int nb = n0 + wn * 64 + cb * 32 + hi * 4 - 2048;
        #pragma unroll
        for (int rg = 0; rg < 4; ++rg) {
          #pragma unroll
          for (int e = 0; e < 4; ++e) {
            int vcol = nb + rg * 8 + e;
            int hh = vcol >> 6, d = vcol & 63;
            VtG[((size_t)(bq * 16 + hh) * 64 + d) * 2048 + key] =
                (bf16)acc[rb][cb][rg * 4 + e];
          }
        }
      }
    }
  }
}

// ---------------- split-K GEMM: Cp[z][M,N] = A[:, zKc:(z+1)Kc] @ Bt^T ----------------
__global__ __launch_bounds__(256) void gemm_splitk(
    const bf16* __restrict__ A, const bf16* __restrict__ Bt,
    bf16* __restrict__ Cp, int M, int N, int Ktot, int Kc)
{
  __shared__ bf16 As[8192];
  __shared__ bf16 Bs[8192];
  const int lane = threadIdx.x & 63, wv = threadIdx.x >> 6;
  const int r = lane & 31, hi = lane >> 5;
  const int m0 = blockIdx.x * 128, n0 = blockIdx.y * 128;
  const int z = blockIdx.z;
  const int wm = wv >> 1, wn = wv & 1;
  floatx16 acc[2][2] = {};
  gemm_core(A + (size_t)m0 * Ktot, Bt + (size_t)n0 * Ktot, Ktot,
            z * Kc, (z + 1) * Kc, As, Bs, acc);
  bf16* C = Cp + (size_t)z * M * N;
  #pragma unroll
  for (int rb = 0; rb < 2; ++rb) {
    int m = m0 + wm * 64 + rb * 32 + r;
    #pragma unroll
    for (int cb = 0; cb < 2; ++cb) {
      int nb = n0 + wn * 64 + cb * 32 + hi * 4;
      #pragma unroll
      for (int rg = 0; rg < 4; ++rg) {
        int n = nb + rg * 8;
        bf16x4 ov = { (bf16)acc[rb][cb][rg * 4 + 0], (bf16)acc[rb][cb][rg * 4 + 1],
                      (bf16)acc[rb][cb][rg * 4 + 2], (bf16)acc[rb][cb][rg * 4 + 3] };
        *(bf16x4*)(C + (size_t)m * N + n) = ov;
      }
    }
  }
}

// ---------------- Wo combine + bias + residual + LN2 (one row/block) ----------------
__global__ __launch_bounds__(256) void combine_wo_ln2(
    const bf16* __restrict__ P, const float* __restrict__ bo,
    const float* __restrict__ x, const float* __restrict__ gam,
    const float* __restrict__ bet, float* __restrict__ x2, bf16* __restrict__ h2)
{
  const int row = blockIdx.x, t = threadIdx.x;
  const size_t base = (size_t)row * 1024 + t * 4;
  float4 v = *(const float4*)(x + base);
  bf16x4 p0 = *(const bf16x4*)(P + base);
  bf16x4 p1 = *(const bf16x4*)(P + 4194304 + base);
  float4 bv = *(const float4*)(bo + t * 4);
  v.x += (float)p0[0] + (float)p1[0] + bv.x;
  v.y += (float)p0[1] + (float)p1[1] + bv.y;
  v.z += (float)p0[2] + (float)p1[2] + bv.z;
  v.w += (float)p0[3] + (float)p1[3] + bv.w;
  *(float4*)(x2 + base) = v;
  float s  = v.x + v.y + v.z + v.w;
  float s2 = v.x * v.x + v.y * v.y + v.z * v.z + v.w * v.w;
  #pragma unroll
  for (int off = 1; off < 64; off <<= 1) {
    s  += __shfl_xor(s, off);
    s2 += __shfl_xor(s2, off);
  }
  __shared__ float ps[4], ps2[4];
  int wv = t >> 6;
  if ((t & 63) == 0) { ps[wv] = s; ps2[wv] = s2; }
  __syncthreads();
  s  = ps[0] + ps[1] + ps[2] + ps[3];
  s2 = ps2[0] + ps2[1] + ps2[2] + ps2[3];
  const float mu = s * (1.0f / 1024.0f);
  const float rstd = rsqrtf(s2 * (1.0f / 1024.0f) - mu * mu + 1e-5f);
  float4 gv = *(const float4*)(gam + t * 4);
  float4 bb = *(const float4*)(bet + t * 4);
  bf16x4 o;
  o[0] = (bf16)((v.x - mu) * rstd * gv.x + bb.x);
  o[1] = (bf16)((v.y - mu) * rstd * gv.y + bb.y);
  o[2] = (bf16)((v.z - mu) * rstd * gv.z + bb.z);
  o[3] = (bf16)((v.w - mu) * rstd * gv.w + bb.w);
  *(bf16x4*)(h2 + base) = o;
}

// ---------------- FFN2 combine: out = sum_z P_z + b2 + x2 ----------------
__global__ __launch_bounds__(256) void combine_ffn2(
    const bf16* __restrict__ P, const float* __restrict__ b2,
    const float* __restrict__ x2, float* __restrict__ out)
{
  const size_t i = ((size_t)blockIdx.x * 256 + threadIdx.x) * 4;
  const int col = (int)(i & 1023);
  float4 acc = *(const float4*)(x2 + i);
  float4 bv = *(const float4*)(b2 + col);
  acc.x += bv.x; acc.y += bv.y; acc.z += bv.z; acc.w += bv.w;
  #pragma unroll
  for (int z = 0; z < 4; ++z) {
    bf16x4 p = *(const bf16x4*)(P + (size_t)z * 4194304 + i);
    acc.x += (float)p[0]; acc.y += (float)p[1];
    acc.z += (float)p[2]; acc.w += (float)p[3];
  }
  *(float4*)(out + i) = acc;
}

// ---------------- flash attention (causal), constant-shift softmax ----------------
__global__ __launch_bounds__(256, 2) void attn_kernel(
    const bf16* __restrict__ qkv, const bf16* __restrict__ VtG,
    bf16* __restrict__ attnb)
{
  __shared__ bf16 Ks[64 * 72];
  __shared__ bf16 Vt[64 * 72];
  const int t = threadIdx.x, lane = t & 63, wv = t >> 6;
  const int li = lane & 15, g = lane >> 4;
  const int p = blockIdx.x & 15, h = (blockIdx.x >> 4) & 15, b = blockIdx.x >> 8;
  const int row0 = b << 11;
  const int tlo = p * 4 + wv, thi = 127 - tlo;
  const int q0l = tlo << 4, q0h = thi << 4;
  const size_t qkvbase = (size_t)row0 * 3072 + (size_t)h * 64;
  const bf16* vgbase = VtG + (size_t)(b * 16 + h) * 64 * 2048;

  const bf16* qpl = qkv + qkvbase + (size_t)(q0l + li) * 3072 + g * 8;
  const bf16* qph = qkv + qkvbase + (size_t)(q0h + li) * 3072 + g * 8;
  bf16x8 bl0 = *(const bf16x8*)(qpl), bl1 = *(const bf16x8*)(qpl + 32);
  bf16x8 bh0 = *(const bf16x8*)(qph), bh1 = *(const bf16x8*)(qph + 32);

  floatx4 ol[4] = {}, oh[4] = {};
  float ll = 0.f, lh = 0.f;
  const int cmax = 31 - p;

  auto proc = [&](const bf16x8& bq0, const bf16x8& bq1, float& l_i,
                  floatx4 (&o)[4], int qg, int k0, bool diag) {
    floatx4 sv[4];
    #pragma unroll
    for (int s = 0; s < 4; ++s) {
      const bf16* kr = Ks + (s * 16 + li) * 72 + g * 8;
      bf16x8 a0 = *(const bf16x8*)(kr);
      bf16x8 a1 = *(const bf16x8*)(kr + 32);
      floatx4 z = {0.f, 0.f, 0.f, 0.f};
      z = __builtin_amdgcn_mfma_f32_16x16x32_bf16(a0, bq0, z, 0, 0, 0);
      z = __builtin_amdgcn_mfma_f32_16x16x32_bf16(a1, bq1, z, 0, 0, 0);
      sv[s] = z;
    }
    float pv[4][4];
    float rs = 0.f;
    #pragma unroll
    for (int s = 0; s < 4; ++s)
      #pragma unroll
      for (int e = 0; e < 4; ++e) {
        float val = __expf(sv[s][e] * 0.125f - 4.0f);
        if (diag) {
          int kg = k0 + s * 16 + g * 4 + e;
          val = (kg <= qg) ? val : 0.0f;
        }
        pv[s][e] = val;
        rs += val;
      }
    rs += __shfl_xor(rs, 16);
    rs += __shfl_xor(rs, 32);
    l_i += rs;
    #pragma unroll
    for (int s = 0; s < 4; ++s) {
      shortx4 bp = { f2bf_bits(pv[s][0]), f2bf_bits(pv[s][1]),
                     f2bf_bits(pv[s][2]), f2bf_bits(pv[s][3]) };
      #pragma unroll
      for (int c = 0; c < 4; ++c) {
        shortx4 av = *(const shortx4*)(Vt + (c * 16 + li) * 72 + s * 16 + g * 4);
        o[c] = __builtin_amdgcn_mfma_f32_16x16x16bf16_1k(av, bp, o[c], 0, 0, 0);
      }
    }
  };

  for (int c = 0; c <= cmax; ++c) {
    {   // stage 64-key chunk: K row-major from qkv, V rows from VtG
      const size_t kb = qkvbase + (size_t)(c * 64) * 3072 + 1024;
      #pragma unroll
      for (int r = 0; r < 2; ++r) {
        int row = r * 32 + (t >> 3), dc = (t & 7) * 8;
        bf16x8 kvv = *(const bf16x8*)(qkv + kb + (size_t)row * 3072 + dc);
        *(bf16x8*)(Ks + row * 72 + dc) = kvv;
      }
      int d = t >> 2, kg = (t & 3) * 16;
      const bf16* vg = vgbase + (size_t)d * 2048 + c * 64 + kg;
      bf16x8 v0 = *(const bf16x8*)(vg);
      bf16x8 v1 = *(const bf16x8*)(vg + 8);
      *(bf16x8*)(Vt + d * 72 + kg)     = v0;
      *(bf16x8*)(Vt + d * 72 + kg + 8) = v1;
    }
    __syncthreads();
    proc(bh0, bh1, lh, oh, q0h + li, c * 64, c == cmax);
    if (c <= p) proc(bl0, bl1, ll, ol, q0l + li, c * 64, c == p);
    __syncthreads();
  }

  const float invh = 1.0f / lh, invl = 1.0f / ll;
  #pragma unroll
  for (int c = 0; c < 4; ++c) {
    bf16x4 ovh = { (bf16)(oh[c][0] * invh), (bf16)(oh[c][1] * invh),
                   (bf16)(oh[c][2] * invh), (bf16)(oh[c][3] * invh) };
    *(bf16x4*)(attnb + (size_t)(row0 + q0h + li) * 1024 + h * 64 + c * 16 + g * 4) = ovh;
    bf16x4 ovl = { (bf16)(ol[c][0] * invl), (bf16)(ol[c][1] * invl),
                   (bf16)(ol[c][2] * invl), (bf16)(ol[c][3] * invl) };
    *(bf16x4*)(attnb + (size_t)(row0 + q0l + li) * 1024 + h * 64 + c * 16 + g * 4) = ovl;
  }
}

// ---------------- launch ----------------
extern "C" void kernel_launch(void* const* d_in, const int* in_sizes, int n_in,
                              void* d_out, int out_size, void* d_ws, size_t ws_size,
                              hipStream_t stream) {
  (void)in_sizes; (void)n_in; (void)out_size; (void)ws_size;
  const float* x    = (const float*)d_in[0];
  const float* Wq   = (const float*)d_in[1];
  const float* Wk   = (const float*)d_in[2];
  const float* Wv   = (const float*)d_in[3];
  const float* Wo   = (const float*)d_in[4];
  const float* bo   = (const float*)d_in[5];
  const float* W1   = (const float*)d_in[6];
  const float* b1   = (const float*)d_in[7];
  const float* W2   = (const float*)d_in[8];
  const float* b2   = (const float*)d_in[9];
  const float* ln1g = (const float*)d_in[10];
  const float* ln1b = (const float*)d_in[11];
  const float* ln2g = (const float*)d_in[12];
  const float* ln2b = (const float*)d_in[13];
  float* out = (float*)d_out;
  char* ws = (char*)d_ws;

  constexpr size_t OFF_WQKVT = 0;
  constexpr size_t OFF_WOT   = OFF_WQKVT + 3072ull * 1024 * 2;
  constexpr size_t OFF_W1T   = OFF_WOT   + 1024ull * 1024 * 2;
  constexpr size_t OFF_W2T   = OFF_W1T   + 4096ull * 1024 * 2;
  constexpr size_t OFF_H1    = OFF_W2T   + 1024ull * 4096 * 2;
  constexpr size_t OFF_QKV   = OFF_H1    + 4096ull * 1024 * 2;
  constexpr size_t OFF_ATT   = OFF_QKV   + 4096ull * 3072 * 2;
  constexpr size_t OFF_X2    = OFF_ATT   + 4096ull * 1024 * 2;
  constexpr size_t OFF_H2    = OFF_X2    + 4096ull * 1024 * 4;
  constexpr size_t OFF_F1    = OFF_H2    + 4096ull * 1024 * 2;
  constexpr size_t OFF_PART  = OFF_F1    + 4096ull * 4096 * 2;      // 4x [4096,1024] bf16
  constexpr size_t OFF_VTG   = OFF_PART  + 4ull * 4096 * 1024 * 2;  // [32][64][2048] bf16

  bf16*  WqkvT = (bf16*)(ws + OFF_WQKVT);
  bf16*  WoT   = (bf16*)(ws + OFF_WOT);
  bf16*  W1T   = (bf16*)(ws + OFF_W1T);
  bf16*  W2T   = (bf16*)(ws + OFF_W2T);
  bf16*  h1    = (bf16*)(ws + OFF_H1);
  bf16*  qkv   = (bf16*)(ws + OFF_QKV);
  bf16*  attnb = (bf16*)(ws + OFF_ATT);
  float* x2    = (float*)(ws + OFF_X2);
  bf16*  h2    = (bf16*)(ws + OFF_H2);
  bf16*  f1    = (bf16*)(ws + OFF_F1);
  bf16*  part  = (bf16*)(ws + OFF_PART);
  bf16*  vtg   = (bf16*)(ws + OFF_VTG);

  prep_kernel<<<16384, 256, 0, stream>>>(Wq, Wk, Wv, Wo, W1, W2,
                                         WqkvT, WoT, W1T, W2T, x, ln1g, ln1b, h1);
  gemm_qkv<<<dim3(32, 24), 256, 0, stream>>>(h1, WqkvT, qkv, vtg);
  attn_kernel<<<512, 256, 0, stream>>>(qkv, vtg, attnb);
  gemm_splitk<<<dim3(32, 8, 2), 256, 0, stream>>>(attnb, WoT, part, 4096, 1024, 1024, 512);
  combine_wo_ln2<<<4096, 256, 0, stream>>>(part, bo, x, ln2g, ln2b, x2, h2);
  gemm_kernel<true, true, false><<<dim3(32, 32), 256, 0, stream>>>(
      h2, W1T, b1, nullptr, f1, nullptr, 4096, 4096, 1024);
  gemm_splitk<<<dim3(32, 8, 4), 256, 0, stream>>>(f1, W2T, part, 4096, 1024, 4096, 1024);
  combine_ffn2<<<4096, 256, 0, stream>>>(part, b2, x2, out);
}

// Round 8
// 360.212 us; speedup vs baseline: 1.0248x; 1.0248x over previous
//
#include <hip/hip_runtime.h>

// Transformer block, B=2 T=2048 D=1024 H=16 HS=64, bf16 MFMA pipeline.
// R8: R7 (BK=64, 32x32x16 MFMA) with CORRECTED LDS chunk swizzle:
//     chunk q=2*kh+hi, rotation rho=(r>>1)&3; staging slot j holds chunk
//     (j+rho)&3, reader fetches slot (q-rho)&3 -> uniform 8-deep banks
//     (parity with the 16x16 pattern) at half the MFMA issue slots.

typedef __bf16 bf16;
typedef __attribute__((ext_vector_type(8)))  __bf16 bf16x8;
typedef __attribute__((ext_vector_type(4)))  __bf16 bf16x4;
typedef __attribute__((ext_vector_type(4)))  short  shortx4;
typedef __attribute__((ext_vector_type(4)))  float  floatx4;
typedef __attribute__((ext_vector_type(16))) float  floatx16;

__device__ __forceinline__ short f2bf_bits(float x) {
  return __builtin_bit_cast(short, (bf16)x);
}

// async global->LDS, 16B per lane. LDS dest is wave-uniform base + lane*16.
__device__ __forceinline__ void gl2lds16(const bf16* g, bf16* l) {
  __builtin_amdgcn_global_load_lds((const __attribute__((address_space(1))) void*)g,
                                   (__attribute__((address_space(3))) void*)l, 16, 0, 0);
}

// ---------------- prep: weight transpose+cvt (ids 0..12287) + LN1 (ids 12288+) ----
__global__ __launch_bounds__(256) void prep_kernel(
    const float* __restrict__ Wq, const float* __restrict__ Wk,
    const float* __restrict__ Wv, const float* __restrict__ Wo,
    const float* __restrict__ W1, const float* __restrict__ W2,
    bf16* __restrict__ WqkvT, bf16* __restrict__ WoT,
    bf16* __restrict__ W1T, bf16* __restrict__ W2T,
    const float* __restrict__ x, const float* __restrict__ ln1g,
    const float* __restrict__ ln1b, bf16* __restrict__ h1)
{
  int id = blockIdx.x;
  if (id >= 12288) {   // ---- LN1 row ----
    const int row = id - 12288, t = threadIdx.x;
    const float* xr = x + (size_t)row * 1024;
    float4 v = *(const float4*)(xr + t * 4);
    float s  = v.x + v.y + v.z + v.w;
    float s2 = v.x * v.x + v.y * v.y + v.z * v.z + v.w * v.w;
    #pragma unroll
    for (int off = 1; off < 64; off <<= 1) {
      s  += __shfl_xor(s, off);
      s2 += __shfl_xor(s2, off);
    }
    __shared__ float ps[4], ps2[4];
    int wv = t >> 6;
    if ((t & 63) == 0) { ps[wv] = s; ps2[wv] = s2; }
    __syncthreads();
    s  = ps[0] + ps[1] + ps[2] + ps[3];
    s2 = ps2[0] + ps2[1] + ps2[2] + ps2[3];
    const float mu = s * (1.0f / 1024.0f);
    const float rstd = rsqrtf(s2 * (1.0f / 1024.0f) - mu * mu + 1e-5f);
    float4 gv = *(const float4*)(ln1g + t * 4);
    float4 bv = *(const float4*)(ln1b + t * 4);
    bf16x4 o;
    o[0] = (bf16)((v.x - mu) * rstd * gv.x + bv.x);
    o[1] = (bf16)((v.y - mu) * rstd * gv.y + bv.y);
    o[2] = (bf16)((v.z - mu) * rstd * gv.z + bv.z);
    o[3] = (bf16)((v.w - mu) * rstd * gv.w + bv.w);
    *(bf16x4*)(h1 + (size_t)row * 1024 + t * 4) = o;
    return;
  }
  // ---- weight transpose tile ----
  const float* src; bf16* dst; int K, N, tile;
  if (id < 4096) {
    K = 1024; N = 1024; tile = id & 1023;
    int wsel = id >> 10;
    src = (wsel == 0) ? Wq : (wsel == 1) ? Wk : (wsel == 2) ? Wv : Wo;
    dst = (wsel < 3) ? (WqkvT + (size_t)wsel * 1024 * 1024) : WoT;
  } else if (id < 8192) {
    K = 1024; N = 4096; tile = id - 4096; src = W1; dst = W1T;
  } else {
    K = 4096; N = 1024; tile = id - 8192; src = W2; dst = W2T;
  }
  int ntn = N >> 5;
  int k0 = (tile / ntn) * 32, n0 = (tile % ntn) * 32;
  __shared__ float tl[32][33];
  int tr = threadIdx.x >> 3, tc = (threadIdx.x & 7) * 4;
  float4 v = *(const float4*)(src + (size_t)(k0 + tr) * N + n0 + tc);
  tl[tr][tc + 0] = v.x; tl[tr][tc + 1] = v.y; tl[tr][tc + 2] = v.z; tl[tr][tc + 3] = v.w;
  __syncthreads();
  bf16x4 o = { (bf16)tl[tc + 0][tr], (bf16)tl[tc + 1][tr],
               (bf16)tl[tc + 2][tr], (bf16)tl[tc + 3][tr] };
  *(bf16x4*)(dst + (size_t)(n0 + tr) * K + k0 + tc) = o;
}

// ---------------- shared GEMM core: BK=64 twin panels, 32x32x16 MFMA -------------
// LDS row (32 k-elems = 4 chunks of 8): slot j holds source chunk (j+rho)&3,
// rho = (row>>1)&3. Reader for chunk q=2*kh+hi reads slot (q-rho)&3.
// acc[rb][cb] = C^T fragment: C-row m = lane&31, C-col n = 8*(reg>>2) +
// 4*(lane>>5) + (reg&3)  [verified R7 pass].
__device__ __forceinline__ void gemm_core(
    const bf16* __restrict__ A, const bf16* __restrict__ Bt,
    int Ktot, int k0, int k1, bf16* As, bf16* Bs, floatx16 (&acc)[2][2])
{
  const int tid = threadIdx.x, lane = tid & 63, wv = tid >> 6;
  const int r = lane & 31, hi = lane >> 5;
  const int wm = wv >> 1, wn = wv & 1;
  const int srow = wv * 16 + (lane >> 2);
  // staging: slot j=lane&3 must hold source chunk (j + rho_srow)&3,
  // rho_srow = (srow>>1)&3 = (lane>>3)&3  (wv*8 == 0 mod 4)
  const int scol = (((lane & 3) + ((lane >> 3) & 3)) & 3) * 8;
  const bf16* aP = A  + (size_t)srow * Ktot + scol;
  const bf16* bP = Bt + (size_t)srow * Ktot + scol;
  bf16* AsW = As + wv * 512;
  bf16* BsW = Bs + wv * 512;
  // reader cols (elems within 32-elem row) for kh=0/1
  const int rho = (r >> 1) & 3;
  const int cc0 = ((hi - rho) & 3) * 8;        // chunk q = hi
  const int cc1 = ((2 + hi - rho) & 3) * 8;    // chunk q = 2 + hi
  const bf16* a0P = As + (wm * 64 + r) * 32;
  const bf16* a1P = As + (wm * 64 + 32 + r) * 32;
  const bf16* b0P = Bs + (wn * 64 + r) * 32;
  const bf16* b1P = Bs + (wn * 64 + 32 + r) * 32;
  for (int kt = k0; kt < k1; kt += 64) {
    gl2lds16(aP + kt,                          AsW);
    gl2lds16(aP + kt + (size_t)64 * Ktot,      AsW + 2048);
    gl2lds16(aP + kt + 32,                     AsW + 4096);
    gl2lds16(aP + kt + 32 + (size_t)64 * Ktot, AsW + 6144);
    gl2lds16(bP + kt,                          BsW);
    gl2lds16(bP + kt + (size_t)64 * Ktot,      BsW + 2048);
    gl2lds16(bP + kt + 32,                     BsW + 4096);
    gl2lds16(bP + kt + 32 + (size_t)64 * Ktot, BsW + 6144);
    __syncthreads();
    #pragma unroll
    for (int h = 0; h < 2; ++h) {
      const int pb = h * 4096;
      #pragma unroll
      for (int kh = 0; kh < 2; ++kh) {
        const int cc = kh ? cc1 : cc0;
        bf16x8 a0 = *(const bf16x8*)(a0P + pb + cc);
        bf16x8 a1 = *(const bf16x8*)(a1P + pb + cc);
        bf16x8 b0 = *(const bf16x8*)(b0P + pb + cc);
        bf16x8 b1 = *(const bf16x8*)(b1P + pb + cc);
        acc[0][0] = __builtin_amdgcn_mfma_f32_32x32x16_bf16(b0, a0, acc[0][0], 0, 0, 0);
        acc[0][1] = __builtin_amdgcn_mfma_f32_32x32x16_bf16(b1, a0, acc[0][1], 0, 0, 0);
        acc[1][0] = __builtin_amdgcn_mfma_f32_32x32x16_bf16(b0, a1, acc[1][0], 0, 0, 0);
        acc[1][1] = __builtin_amdgcn_mfma_f32_32x32x16_bf16(b1, a1, acc[1][1], 0, 0, 0);
      }
    }
    __syncthreads();
  }
}

// ---------------- GEMM: C[M,N] = A[M,K] @ Bt[N,K]^T ----------------
template<bool BIAS, bool RELU, bool RESID>
__global__ __launch_bounds__(256) void gemm_kernel(
    const bf16* __restrict__ A, const bf16* __restrict__ Bt,
    const float* __restrict__ bias, const float* __restrict__ resid,
    bf16* __restrict__ Cb, float* __restrict__ Cf,
    int M, int N, int K)
{
  __shared__ bf16 As[8192];
  __shared__ bf16 Bs[8192];
  const int lane = threadIdx.x & 63, wv = threadIdx.x >> 6;
  const int r = lane & 31, hi = lane >> 5;
  const int m0 = blockIdx.x * 128, n0 = blockIdx.y * 128;
  const int wm = wv >> 1, wn = wv & 1;
  floatx16 acc[2][2] = {};
  gemm_core(A + (size_t)m0 * K, Bt + (size_t)n0 * K, K, 0, K, As, Bs, acc);
  #pragma unroll
  for (int rb = 0; rb < 2; ++rb) {
    int m = m0 + wm * 64 + rb * 32 + r;
    #pragma unroll
    for (int cb = 0; cb < 2; ++cb) {
      int nb = n0 + wn * 64 + cb * 32 + hi * 4;
      #pragma unroll
      for (int rg = 0; rg < 4; ++rg) {
        int n = nb + rg * 8;
        float4 bv = BIAS ? *(const float4*)(bias + n) : float4{0, 0, 0, 0};
        float v0 = acc[rb][cb][rg * 4 + 0] + bv.x;
        float v1 = acc[rb][cb][rg * 4 + 1] + bv.y;
        float v2 = acc[rb][cb][rg * 4 + 2] + bv.z;
        float v3 = acc[rb][cb][rg * 4 + 3] + bv.w;
        if (RELU) {
          v0 = fmaxf(v0, 0.f); v1 = fmaxf(v1, 0.f);
          v2 = fmaxf(v2, 0.f); v3 = fmaxf(v3, 0.f);
        }
        size_t idx = (size_t)m * N + n;
        if (RESID) {
          float4 rv = *(const float4*)(resid + idx);
          float4 ov = { v0 + rv.x, v1 + rv.y, v2 + rv.z, v3 + rv.w };
          *(float4*)(Cf + idx) = ov;
        } else {
          bf16x4 ov = { (bf16)v0, (bf16)v1, (bf16)v2, (bf16)v3 };
          *(bf16x4*)(Cb + idx) = ov;
        }
      }
    }
  }
}

// ---------------- QKV GEMM: Q,K -> qkv row-major; V -> VtG[b*16+h][d][key] ----------
__global__ __launch_bounds__(256) void gemm_qkv(
    const bf16* __restrict__ A, const bf16* __restrict__ Bt,
    bf16* __restrict__ qkv, bf16* __restrict__ VtG)
{
  const int K = 1024;
  __shared__ bf16 As[8192];
  __shared__ bf16 Bs[8192];
  const int lane = threadIdx.x & 63, wv = threadIdx.x >> 6;
  const int r = lane & 31, hi = lane >> 5;
  const int m0 = blockIdx.x * 128, n0 = blockIdx.y * 128;
  const int wm = wv >> 1, wn = wv & 1;
  floatx16 acc[2][2] = {};
  gemm_core(A + (size_t)m0 * K, Bt + (size_t)n0 * K, K, 0, K, As, Bs, acc);
  if (n0 < 2048) {   // Q,K block: row-major vector stores into qkv
    #pragma unroll
    for (int rb = 0; rb < 2; ++rb) {
      int m = m0 + wm * 64 + rb * 32 + r;
      #pragma unroll
      for (int cb = 0; cb < 2; ++cb) {
        int nb = n0 + wn * 64 + cb * 32 + hi * 4;
        #pragma unroll
        for (int rg = 0; rg < 4; ++rg) {
          int n = nb + rg * 8;
          bf16x4 ov = { (bf16)acc[rb][cb][rg * 4 + 0], (bf16)acc[rb][cb][rg * 4 + 1],
                        (bf16)acc[rb][cb][rg * 4 + 2], (bf16)acc[rb][cb][rg * 4 + 3] };
          *(bf16x4*)(qkv + (size_t)m * 3072 + n) = ov;
        }
      }
    }
  } else {           // V block: scatter transposed into VtG (lanes walk keys)
    #pragma unroll
    for (int rb = 0; rb < 2; ++rb) {
      int m = m0 + wm * 64 + rb * 32 + r;
      int key = m & 2047, bq = m >> 11;
      #pragma unroll
      for (int cb = 0; cb < 2; ++cb) {
        int nb = n0 + wn * 64 + cb * 32 + hi * 4 - 2048;
        #pragma unroll
        for (int rg = 0; rg < 4; ++rg) {
          #pragma unroll
          for (int e = 0; e < 4; ++e) {
            int vcol = nb + rg * 8 + e;
            int hh = vcol >> 6, d = vcol & 63;
            VtG[((size_t)(bq * 16 + hh) * 64 + d) * 2048 + key] =
                (bf16)acc[rb][cb][rg * 4 + e];
          }
        }
      }
    }
  }
}

// ---------------- split-K GEMM: Cp[z][M,N] = A[:, zKc:(z+1)Kc] @ Bt^T ----------------
__global__ __launch_bounds__(256) void gemm_splitk(
    const bf16* __restrict__ A, const bf16* __restrict__ Bt,
    bf16* __restrict__ Cp, int M, int N, int Ktot, int Kc)
{
  __shared__ bf16 As[8192];
  __shared__ bf16 Bs[8192];
  const int lane = threadIdx.x & 63, wv = threadIdx.x >> 6;
  const int r = lane & 31, hi = lane >> 5;
  const int m0 = blockIdx.x * 128, n0 = blockIdx.y * 128;
  const int z = blockIdx.z;
  const int wm = wv >> 1, wn = wv & 1;
  floatx16 acc[2][2] = {};
  gemm_core(A + (size_t)m0 * Ktot, Bt + (size_t)n0 * Ktot, Ktot,
            z * Kc, (z + 1) * Kc, As, Bs, acc);
  bf16* C = Cp + (size_t)z * M * N;
  #pragma unroll
  for (int rb = 0; rb < 2; ++rb) {
    int m = m0 + wm * 64 + rb * 32 + r;
    #pragma unroll
    for (int cb = 0; cb < 2; ++cb) {
      int nb = n0 + wn * 64 + cb * 32 + hi * 4;
      #pragma unroll
      for (int rg = 0; rg < 4; ++rg) {
        int n = nb + rg * 8;
        bf16x4 ov = { (bf16)acc[rb][cb][rg * 4 + 0], (bf16)acc[rb][cb][rg * 4 + 1],
                      (bf16)acc[rb][cb][rg * 4 + 2], (bf16)acc[rb][cb][rg * 4 + 3] };
        *(bf16x4*)(C + (size_t)m * N + n) = ov;
      }
    }
  }
}

// ---------------- Wo combine + bias + residual + LN2 (one row/block) ----------------
__global__ __launch_bounds__(256) void combine_wo_ln2(
    const bf16* __restrict__ P, const float* __restrict__ bo,
    const float* __restrict__ x, const float* __restrict__ gam,
    const float* __restrict__ bet, float* __restrict__ x2, bf16* __restrict__ h2)
{
  const int row = blockIdx.x, t = threadIdx.x;
  const size_t base = (size_t)row * 1024 + t * 4;
  float4 v = *(const float4*)(x + base);
  bf16x4 p0 = *(const bf16x4*)(P + base);
  bf16x4 p1 = *(const bf16x4*)(P + 4194304 + base);
  float4 bv = *(const float4*)(bo + t * 4);
  v.x += (float)p0[0] + (float)p1[0] + bv.x;
  v.y += (float)p0[1] + (float)p1[1] + bv.y;
  v.z += (float)p0[2] + (float)p1[2] + bv.z;
  v.w += (float)p0[3] + (float)p1[3] + bv.w;
  *(float4*)(x2 + base) = v;
  float s  = v.x + v.y + v.z + v.w;
  float s2 = v.x * v.x + v.y * v.y + v.z * v.z + v.w * v.w;
  #pragma unroll
  for (int off = 1; off < 64; off <<= 1) {
    s  += __shfl_xor(s, off);
    s2 += __shfl_xor(s2, off);
  }
  __shared__ float ps[4], ps2[4];
  int wv = t >> 6;
  if ((t & 63) == 0) { ps[wv] = s; ps2[wv] = s2; }
  __syncthreads();
  s  = ps[0] + ps[1] + ps[2] + ps[3];
  s2 = ps2[0] + ps2[1] + ps2[2] + ps2[3];
  const float mu = s * (1.0f / 1024.0f);
  const float rstd = rsqrtf(s2 * (1.0f / 1024.0f) - mu * mu + 1e-5f);
  float4 gv = *(const float4*)(gam + t * 4);
  float4 bb = *(const float4*)(bet + t * 4);
  bf16x4 o;
  o[0] = (bf16)((v.x - mu) * rstd * gv.x + bb.x);
  o[1] = (bf16)((v.y - mu) * rstd * gv.y + bb.y);
  o[2] = (bf16)((v.z - mu) * rstd * gv.z + bb.z);
  o[3] = (bf16)((v.w - mu) * rstd * gv.w + bb.w);
  *(bf16x4*)(h2 + base) = o;
}

// ---------------- FFN2 combine: out = sum_z P_z + b2 + x2 ----------------
__global__ __launch_bounds__(256) void combine_ffn2(
    const bf16* __restrict__ P, const float* __restrict__ b2,
    const float* __restrict__ x2, float* __restrict__ out)
{
  const size_t i = ((size_t)blockIdx.x * 256 + threadIdx.x) * 4;
  const int col = (int)(i & 1023);
  float4 acc = *(const float4*)(x2 + i);
  float4 bv = *(const float4*)(b2 + col);
  acc.x += bv.x; acc.y += bv.y; acc.z += bv.z; acc.w += bv.w;
  #pragma unroll
  for (int z = 0; z < 4; ++z) {
    bf16x4 p = *(const bf16x4*)(P + (size_t)z * 4194304 + i);
    acc.x += (float)p[0]; acc.y += (float)p[1];
    acc.z += (float)p[2]; acc.w += (float)p[3];
  }
  *(float4*)(out + i) = acc;
}

// ---------------- flash attention (causal), constant-shift softmax ----------------
__global__ __launch_bounds__(256, 2) void attn_kernel(
    const bf16* __restrict__ qkv, const bf16* __restrict__ VtG,
    bf16* __restrict__ attnb)
{
  __shared__ bf16 Ks[64 * 72];
  __shared__ bf16 Vt[64 * 72];
  const int t = threadIdx.x, lane = t & 63, wv = t >> 6;
  const int li = lane & 15, g = lane >> 4;
  const int p = blockIdx.x & 15, h = (blockIdx.x >> 4) & 15, b = blockIdx.x >> 8;
  const int row0 = b << 11;
  const int tlo = p * 4 + wv, thi = 127 - tlo;
  const int q0l = tlo << 4, q0h = thi << 4;
  const size_t qkvbase = (size_t)row0 * 3072 + (size_t)h * 64;
  const bf16* vgbase = VtG + (size_t)(b * 16 + h) * 64 * 2048;

  const bf16* qpl = qkv + qkvbase + (size_t)(q0l + li) * 3072 + g * 8;
  const bf16* qph = qkv + qkvbase + (size_t)(q0h + li) * 3072 + g * 8;
  bf16x8 bl0 = *(const bf16x8*)(qpl), bl1 = *(const bf16x8*)(qpl + 32);
  bf16x8 bh0 = *(const bf16x8*)(qph), bh1 = *(const bf16x8*)(qph + 32);

  floatx4 ol[4] = {}, oh[4] = {};
  float ll = 0.f, lh = 0.f;
  const int cmax = 31 - p;

  auto proc = [&](const bf16x8& bq0, const bf16x8& bq1, float& l_i,
                  floatx4 (&o)[4], int qg, int k0, bool diag) {
    floatx4 sv[4];
    #pragma unroll
    for (int s = 0; s < 4; ++s) {
      const bf16* kr = Ks + (s * 16 + li) * 72 + g * 8;
      bf16x8 a0 = *(const bf16x8*)(kr);
      bf16x8 a1 = *(const bf16x8*)(kr + 32);
      floatx4 z = {0.f, 0.f, 0.f, 0.f};
      z = __builtin_amdgcn_mfma_f32_16x16x32_bf16(a0, bq0, z, 0, 0, 0);
      z = __builtin_amdgcn_mfma_f32_16x16x32_bf16(a1, bq1, z, 0, 0, 0);
      sv[s] = z;
    }
    float pv[4][4];
    float rs = 0.f;
    #pragma unroll
    for (int s = 0; s < 4; ++s)
      #pragma unroll
      for (int e = 0; e < 4; ++e) {
        float val = __expf(sv[s][e] * 0.125f - 4.0f);
        if (diag) {
          int kg = k0 + s * 16 + g * 4 + e;
          val = (kg <= qg) ? val : 0.0f;
        }
        pv[s][e] = val;
        rs += val;
      }
    rs += __shfl_xor(rs, 16);
    rs += __shfl_xor(rs, 32);
    l_i += rs;
    #pragma unroll
    for (int s = 0; s < 4; ++s) {
      shortx4 bp = { f2bf_bits(pv[s][0]), f2bf_bits(pv[s][1]),
                     f2bf_bits(pv[s][2]), f2bf_bits(pv[s][3]) };
      #pragma unroll
      for (int c = 0; c < 4; ++c) {
        shortx4 av = *(const shortx4*)(Vt + (c * 16 + li) * 72 + s * 16 + g * 4);
        o[c] = __builtin_amdgcn_mfma_f32_16x16x16bf16_1k(av, bp, o[c], 0, 0, 0);
      }
    }
  };

  for (int c = 0; c <= cmax; ++c) {
    {   // stage 64-key chunk: K row-major from qkv, V rows from VtG
      const size_t kb = qkvbase + (size_t)(c * 64) * 3072 + 1024;
      #pragma unroll
      for (int r = 0; r < 2; ++r) {
        int row = r * 32 + (t >> 3), dc = (t & 7) * 8;
        bf16x8 kvv = *(const bf16x8*)(qkv + kb + (size_t)row * 3072 + dc);
        *(bf16x8*)(Ks + row * 72 + dc) = kvv;
      }
      int d = t >> 2, kg = (t & 3) * 16;
      const bf16* vg = vgbase + (size_t)d * 2048 + c * 64 + kg;
      bf16x8 v0 = *(const bf16x8*)(vg);
      bf16x8 v1 = *(const bf16x8*)(vg + 8);
      *(bf16x8*)(Vt + d * 72 + kg)     = v0;
      *(bf16x8*)(Vt + d * 72 + kg + 8) = v1;
    }
    __syncthreads();
    proc(bh0, bh1, lh, oh, q0h + li, c * 64, c == cmax);
    if (c <= p) proc(bl0, bl1, ll, ol, q0l + li, c * 64, c == p);
    __syncthreads();
  }

  const float invh = 1.0f / lh, invl = 1.0f / ll;
  #pragma unroll
  for (int c = 0; c < 4; ++c) {
    bf16x4 ovh = { (bf16)(oh[c][0] * invh), (bf16)(oh[c][1] * invh),
                   (bf16)(oh[c][2] * invh), (bf16)(oh[c][3] * invh) };
    *(bf16x4*)(attnb + (size_t)(row0 + q0h + li) * 1024 + h * 64 + c * 16 + g * 4) = ovh;
    bf16x4 ovl = { (bf16)(ol[c][0] * invl), (bf16)(ol[c][1] * invl),
                   (bf16)(ol[c][2] * invl), (bf16)(ol[c][3] * invl) };
    *(bf16x4*)(attnb + (size_t)(row0 + q0l + li) * 1024 + h * 64 + c * 16 + g * 4) = ovl;
  }
}

// ---------------- launch ----------------
extern "C" void kernel_launch(void* const* d_in, const int* in_sizes, int n_in,
                              void* d_out, int out_size, void* d_ws, size_t ws_size,
                              hipStream_t stream) {
  (void)in_sizes; (void)n_in; (void)out_size; (void)ws_size;
  const float* x    = (const float*)d_in[0];
  const float* Wq   = (const float*)d_in[1];
  const float* Wk   = (const float*)d_in[2];
  const float* Wv   = (const float*)d_in[3];
  const float* Wo   = (const float*)d_in[4];
  const float* bo   = (const float*)d_in[5];
  const float* W1   = (const float*)d_in[6];
  const float* b1   = (const float*)d_in[7];
  const float* W2   = (const float*)d_in[8];
  const float* b2   = (const float*)d_in[9];
  const float* ln1g = (const float*)d_in[10];
  const float* ln1b = (const float*)d_in[11];
  const float* ln2g = (const float*)d_in[12];
  const float* ln2b = (const float*)d_in[13];
  float* out = (float*)d_out;
  char* ws = (char*)d_ws;

  constexpr size_t OFF_WQKVT = 0;
  constexpr size_t OFF_WOT   = OFF_WQKVT + 3072ull * 1024 * 2;
  constexpr size_t OFF_W1T   = OFF_WOT   + 1024ull * 1024 * 2;
  constexpr size_t OFF_W2T   = OFF_W1T   + 4096ull * 1024 * 2;
  constexpr size_t OFF_H1    = OFF_W2T   + 1024ull * 4096 * 2;
  constexpr size_t OFF_QKV   = OFF_H1    + 4096ull * 1024 * 2;
  constexpr size_t OFF_ATT   = OFF_QKV   + 4096ull * 3072 * 2;
  constexpr size_t OFF_X2    = OFF_ATT   + 4096ull * 1024 * 2;
  constexpr size_t OFF_H2    = OFF_X2    + 4096ull * 1024 * 4;
  constexpr size_t OFF_F1    = OFF_H2    + 4096ull * 1024 * 2;
  constexpr size_t OFF_PART  = OFF_F1    + 4096ull * 4096 * 2;      // 4x [4096,1024] bf16
  constexpr size_t OFF_VTG   = OFF_PART  + 4ull * 4096 * 1024 * 2;  // [32][64][2048] bf16

  bf16*  WqkvT = (bf16*)(ws + OFF_WQKVT);
  bf16*  WoT   = (bf16*)(ws + OFF_WOT);
  bf16*  W1T   = (bf16*)(ws + OFF_W1T);
  bf16*  W2T   = (bf16*)(ws + OFF_W2T);
  bf16*  h1    = (bf16*)(ws + OFF_H1);
  bf16*  qkv   = (bf16*)(ws + OFF_QKV);
  bf16*  attnb = (bf16*)(ws + OFF_ATT);
  float* x2    = (float*)(ws + OFF_X2);
  bf16*  h2    = (bf16*)(ws + OFF_H2);
  bf16*  f1    = (bf16*)(ws + OFF_F1);
  bf16*  part  = (bf16*)(ws + OFF_PART);
  bf16*  vtg   = (bf16*)(ws + OFF_VTG);

  prep_kernel<<<16384, 256, 0, stream>>>(Wq, Wk, Wv, Wo, W1, W2,
                                         WqkvT, WoT, W1T, W2T, x, ln1g, ln1b, h1);
  gemm_qkv<<<dim3(32, 24), 256, 0, stream>>>(h1, WqkvT, qkv, vtg);
  attn_kernel<<<512, 256, 0, stream>>>(qkv, vtg, attnb);
  gemm_splitk<<<dim3(32, 8, 2), 256, 0, stream>>>(attnb, WoT, part, 4096, 1024, 1024, 512);
  combine_wo_ln2<<<4096, 256, 0, stream>>>(part, bo, x, ln2g, ln2b, x2, h2);
  gemm_kernel<true, true, false><<<dim3(32, 32), 256, 0, stream>>>(
      h2, W1T, b1, nullptr, f1, nullptr, 4096, 4096, 1024);
  gemm_splitk<<<dim3(32, 8, 4), 256, 0, stream>>>(f1, W2T, part, 4096, 1024, 4096, 1024);
  combine_ffn2<<<4096, 256, 0, stream>>>(part, b2, x2, out);
}

// Round 9
// 347.802 us; speedup vs baseline: 1.0614x; 1.0357x over previous
//
#include <hip/hip_runtime.h>

// Transformer block, B=2 T=2048 D=1024 H=16 HS=64, bf16 MFMA pipeline.
// R9: gemm_core reverted to R5 (16x16x32, BK=64 twin panels - proven best).
//     Attention: software-pipelined K/V staging - next chunk's global loads
//     issue into REGISTERS before compute, LDS writes after compute, double
//     LDS buffer, ONE barrier per chunk -> staging latency hidden.

typedef __bf16 bf16;
typedef __attribute__((ext_vector_type(8))) __bf16 bf16x8;
typedef __attribute__((ext_vector_type(4))) __bf16 bf16x4;
typedef __attribute__((ext_vector_type(4))) short  shortx4;
typedef __attribute__((ext_vector_type(4))) float  floatx4;

__device__ __forceinline__ short f2bf_bits(float x) {
  return __builtin_bit_cast(short, (bf16)x);
}

// async global->LDS, 16B per lane. LDS dest is wave-uniform base + lane*16.
__device__ __forceinline__ void gl2lds16(const bf16* g, bf16* l) {
  __builtin_amdgcn_global_load_lds((const __attribute__((address_space(1))) void*)g,
                                   (__attribute__((address_space(3))) void*)l, 16, 0, 0);
}

// ---------------- prep: weight transpose+cvt (ids 0..12287) + LN1 (ids 12288+) ----
__global__ __launch_bounds__(256) void prep_kernel(
    const float* __restrict__ Wq, const float* __restrict__ Wk,
    const float* __restrict__ Wv, const float* __restrict__ Wo,
    const float* __restrict__ W1, const float* __restrict__ W2,
    bf16* __restrict__ WqkvT, bf16* __restrict__ WoT,
    bf16* __restrict__ W1T, bf16* __restrict__ W2T,
    const float* __restrict__ x, const float* __restrict__ ln1g,
    const float* __restrict__ ln1b, bf16* __restrict__ h1)
{
  int id = blockIdx.x;
  if (id >= 12288) {   // ---- LN1 row ----
    const int row = id - 12288, t = threadIdx.x;
    const float* xr = x + (size_t)row * 1024;
    float4 v = *(const float4*)(xr + t * 4);
    float s  = v.x + v.y + v.z + v.w;
    float s2 = v.x * v.x + v.y * v.y + v.z * v.z + v.w * v.w;
    #pragma unroll
    for (int off = 1; off < 64; off <<= 1) {
      s  += __shfl_xor(s, off);
      s2 += __shfl_xor(s2, off);
    }
    __shared__ float ps[4], ps2[4];
    int wv = t >> 6;
    if ((t & 63) == 0) { ps[wv] = s; ps2[wv] = s2; }
    __syncthreads();
    s  = ps[0] + ps[1] + ps[2] + ps[3];
    s2 = ps2[0] + ps2[1] + ps2[2] + ps2[3];
    const float mu = s * (1.0f / 1024.0f);
    const float rstd = rsqrtf(s2 * (1.0f / 1024.0f) - mu * mu + 1e-5f);
    float4 gv = *(const float4*)(ln1g + t * 4);
    float4 bv = *(const float4*)(ln1b + t * 4);
    bf16x4 o;
    o[0] = (bf16)((v.x - mu) * rstd * gv.x + bv.x);
    o[1] = (bf16)((v.y - mu) * rstd * gv.y + bv.y);
    o[2] = (bf16)((v.z - mu) * rstd * gv.z + bv.z);
    o[3] = (bf16)((v.w - mu) * rstd * gv.w + bv.w);
    *(bf16x4*)(h1 + (size_t)row * 1024 + t * 4) = o;
    return;
  }
  // ---- weight transpose tile ----
  const float* src; bf16* dst; int K, N, tile;
  if (id < 4096) {
    K = 1024; N = 1024; tile = id & 1023;
    int wsel = id >> 10;
    src = (wsel == 0) ? Wq : (wsel == 1) ? Wk : (wsel == 2) ? Wv : Wo;
    dst = (wsel < 3) ? (WqkvT + (size_t)wsel * 1024 * 1024) : WoT;
  } else if (id < 8192) {
    K = 1024; N = 4096; tile = id - 4096; src = W1; dst = W1T;
  } else {
    K = 4096; N = 1024; tile = id - 8192; src = W2; dst = W2T;
  }
  int ntn = N >> 5;
  int k0 = (tile / ntn) * 32, n0 = (tile % ntn) * 32;
  __shared__ float tl[32][33];
  int tr = threadIdx.x >> 3, tc = (threadIdx.x & 7) * 4;
  float4 v = *(const float4*)(src + (size_t)(k0 + tr) * N + n0 + tc);
  tl[tr][tc + 0] = v.x; tl[tr][tc + 1] = v.y; tl[tr][tc + 2] = v.z; tl[tr][tc + 3] = v.w;
  __syncthreads();
  bf16x4 o = { (bf16)tl[tc + 0][tr], (bf16)tl[tc + 1][tr],
               (bf16)tl[tc + 2][tr], (bf16)tl[tc + 3][tr] };
  *(bf16x4*)(dst + (size_t)(n0 + tr) * K + k0 + tc) = o;
}

// ---------------- shared GEMM core: BK=64 via twin 32-col panels (R5) -------------
__device__ __forceinline__ void gemm_core(
    const bf16* __restrict__ A, const bf16* __restrict__ Bt,
    int Ktot, int k0, int k1, bf16* As, bf16* Bs, floatx4 (&acc)[4][4])
{
  const int tid = threadIdx.x, lane = tid & 63, wv = tid >> 6;
  const int li = lane & 15, g = lane >> 4;
  const int wm = wv >> 1, wn = wv & 1;
  const int srow = wv * 16 + (lane >> 2);
  const int scol = (lane & 3) * 8;
  const bf16* aP = A  + (size_t)srow * Ktot + scol;
  const bf16* bP = Bt + (size_t)srow * Ktot + scol;
  bf16* AsW = As + wv * 512;
  bf16* BsW = Bs + wv * 512;
  for (int kt = k0; kt < k1; kt += 64) {
    gl2lds16(aP + kt,                          AsW);
    gl2lds16(aP + kt + (size_t)64 * Ktot,      AsW + 2048);
    gl2lds16(aP + kt + 32,                     AsW + 4096);
    gl2lds16(aP + kt + 32 + (size_t)64 * Ktot, AsW + 6144);
    gl2lds16(bP + kt,                          BsW);
    gl2lds16(bP + kt + (size_t)64 * Ktot,      BsW + 2048);
    gl2lds16(bP + kt + 32,                     BsW + 4096);
    gl2lds16(bP + kt + 32 + (size_t)64 * Ktot, BsW + 6144);
    __syncthreads();
    #pragma unroll
    for (int hh = 0; hh < 2; ++hh) {
      const bf16* Ap = As + hh * 4096;
      const bf16* Bp = Bs + hh * 4096;
      bf16x8 af[4], bfr[4];
      #pragma unroll
      for (int r = 0; r < 4; ++r)
        af[r] = *(const bf16x8*)(Ap + (wm * 64 + r * 16 + li) * 32 + g * 8);
      #pragma unroll
      for (int c = 0; c < 4; ++c)
        bfr[c] = *(const bf16x8*)(Bp + (wn * 64 + c * 16 + li) * 32 + g * 8);
      #pragma unroll
      for (int r = 0; r < 4; ++r)
        #pragma unroll
        for (int c = 0; c < 4; ++c)
          acc[r][c] = __builtin_amdgcn_mfma_f32_16x16x32_bf16(bfr[c], af[r], acc[r][c], 0, 0, 0);
    }
    __syncthreads();
  }
}

// ---------------- GEMM: C[M,N] = A[M,K] @ Bt[N,K]^T ----------------
template<bool BIAS, bool RELU, bool RESID>
__global__ __launch_bounds__(256) void gemm_kernel(
    const bf16* __restrict__ A, const bf16* __restrict__ Bt,
    const float* __restrict__ bias, const float* __restrict__ resid,
    bf16* __restrict__ Cb, float* __restrict__ Cf,
    int M, int N, int K)
{
  __shared__ bf16 As[8192];
  __shared__ bf16 Bs[8192];
  const int lane = threadIdx.x & 63, wv = threadIdx.x >> 6;
  const int li = lane & 15, g = lane >> 4;
  const int m0 = blockIdx.x * 128, n0 = blockIdx.y * 128;
  const int wm = wv >> 1, wn = wv & 1;
  floatx4 acc[4][4] = {};
  gemm_core(A + (size_t)m0 * K, Bt + (size_t)n0 * K, K, 0, K, As, Bs, acc);
  #pragma unroll
  for (int r = 0; r < 4; ++r) {
    int rowC = m0 + wm * 64 + r * 16 + li;
    #pragma unroll
    for (int c = 0; c < 4; ++c) {
      int colC = n0 + wn * 64 + c * 16 + g * 4;
      float4 bv = BIAS ? *(const float4*)(bias + colC) : float4{0, 0, 0, 0};
      float v0 = acc[r][c][0] + bv.x, v1 = acc[r][c][1] + bv.y;
      float v2 = acc[r][c][2] + bv.z, v3 = acc[r][c][3] + bv.w;
      if (RELU) {
        v0 = fmaxf(v0, 0.f); v1 = fmaxf(v1, 0.f);
        v2 = fmaxf(v2, 0.f); v3 = fmaxf(v3, 0.f);
      }
      size_t idx = (size_t)rowC * N + colC;
      if (RESID) {
        float4 rv = *(const float4*)(resid + idx);
        float4 ov = { v0 + rv.x, v1 + rv.y, v2 + rv.z, v3 + rv.w };
        *(float4*)(Cf + idx) = ov;
      } else {
        bf16x4 ov = { (bf16)v0, (bf16)v1, (bf16)v2, (bf16)v3 };
        *(bf16x4*)(Cb + idx) = ov;
      }
    }
  }
}

// ---------------- QKV GEMM: Q,K -> qkv row-major; V -> VtG[b*16+h][d][key] ----------
__global__ __launch_bounds__(256) void gemm_qkv(
    const bf16* __restrict__ A, const bf16* __restrict__ Bt,
    bf16* __restrict__ qkv, bf16* __restrict__ VtG)
{
  const int K = 1024;
  __shared__ bf16 As[8192];
  __shared__ bf16 Bs[8192];
  const int lane = threadIdx.x & 63, wv = threadIdx.x >> 6;
  const int li = lane & 15, g = lane >> 4;
  const int m0 = blockIdx.x * 128, n0 = blockIdx.y * 128;
  const int wm = wv >> 1, wn = wv & 1;
  floatx4 acc[4][4] = {};
  gemm_core(A + (size_t)m0 * K, Bt + (size_t)n0 * K, K, 0, K, As, Bs, acc);
  if (n0 < 2048) {   // Q,K block: row-major vector stores into qkv
    #pragma unroll
    for (int r = 0; r < 4; ++r) {
      int rowC = m0 + wm * 64 + r * 16 + li;
      #pragma unroll
      for (int c = 0; c < 4; ++c) {
        int colC = n0 + wn * 64 + c * 16 + g * 4;
        bf16x4 ov = { (bf16)acc[r][c][0], (bf16)acc[r][c][1],
                      (bf16)acc[r][c][2], (bf16)acc[r][c][3] };
        *(bf16x4*)(qkv + (size_t)rowC * 3072 + colC) = ov;
      }
    }
  } else {           // V block: scatter transposed into VtG (lanes walk keys)
    #pragma unroll
    for (int r = 0; r < 4; ++r) {
      int rowC = m0 + wm * 64 + r * 16 + li;
      int key = rowC & 2047, bq = rowC >> 11;
      #pragma unroll
      for (int c = 0; c < 4; ++c) {
        int vcol0 = n0 + wn * 64 + c * 16 + g * 4 - 2048;
        #pragma unroll
        for (int e = 0; e < 4; ++e) {
          int vcol = vcol0 + e;
          int hh = vcol >> 6, d = vcol & 63;
          VtG[((size_t)(bq * 16 + hh) * 64 + d) * 2048 + key] = (bf16)acc[r][c][e];
        }
      }
    }
  }
}

// ---------------- split-K GEMM: Cp[z][M,N] = A[:, zKc:(z+1)Kc] @ Bt^T ----------------
__global__ __launch_bounds__(256) void gemm_splitk(
    const bf16* __restrict__ A, const bf16* __restrict__ Bt,
    bf16* __restrict__ Cp, int M, int N, int Ktot, int Kc)
{
  __shared__ bf16 As[8192];
  __shared__ bf16 Bs[8192];
  const int lane = threadIdx.x & 63, wv = threadIdx.x >> 6;
  const int li = lane & 15, g = lane >> 4;
  const int m0 = blockIdx.x * 128, n0 = blockIdx.y * 128;
  const int z = blockIdx.z;
  const int wm = wv >> 1, wn = wv & 1;
  floatx4 acc[4][4] = {};
  gemm_core(A + (size_t)m0 * Ktot, Bt + (size_t)n0 * Ktot, Ktot,
            z * Kc, (z + 1) * Kc, As, Bs, acc);
  bf16* C = Cp + (size_t)z * M * N;
  #pragma unroll
  for (int r = 0; r < 4; ++r) {
    int rowC = m0 + wm * 64 + r * 16 + li;
    #pragma unroll
    for (int c = 0; c < 4; ++c) {
      int colC = n0 + wn * 64 + c * 16 + g * 4;
      bf16x4 ov = { (bf16)acc[r][c][0], (bf16)acc[r][c][1],
                    (bf16)acc[r][c][2], (bf16)acc[r][c][3] };
      *(bf16x4*)(C + (size_t)rowC * N + colC) = ov;
    }
  }
}

// ---------------- Wo combine + bias + residual + LN2 (one row/block) ----------------
__global__ __launch_bounds__(256) void combine_wo_ln2(
    const bf16* __restrict__ P, const float* __restrict__ bo,
    const float* __restrict__ x, const float* __restrict__ gam,
    const float* __restrict__ bet, float* __restrict__ x2, bf16* __restrict__ h2)
{
  const int row = blockIdx.x, t = threadIdx.x;
  const size_t base = (size_t)row * 1024 + t * 4;
  float4 v = *(const float4*)(x + base);
  bf16x4 p0 = *(const bf16x4*)(P + base);
  bf16x4 p1 = *(const bf16x4*)(P + 4194304 + base);
  float4 bv = *(const float4*)(bo + t * 4);
  v.x += (float)p0[0] + (float)p1[0] + bv.x;
  v.y += (float)p0[1] + (float)p1[1] + bv.y;
  v.z += (float)p0[2] + (float)p1[2] + bv.z;
  v.w += (float)p0[3] + (float)p1[3] + bv.w;
  *(float4*)(x2 + base) = v;
  float s  = v.x + v.y + v.z + v.w;
  float s2 = v.x * v.x + v.y * v.y + v.z * v.z + v.w * v.w;
  #pragma unroll
  for (int off = 1; off < 64; off <<= 1) {
    s  += __shfl_xor(s, off);
    s2 += __shfl_xor(s2, off);
  }
  __shared__ float ps[4], ps2[4];
  int wv = t >> 6;
  if ((t & 63) == 0) { ps[wv] = s; ps2[wv] = s2; }
  __syncthreads();
  s  = ps[0] + ps[1] + ps[2] + ps[3];
  s2 = ps2[0] + ps2[1] + ps2[2] + ps2[3];
  const float mu = s * (1.0f / 1024.0f);
  const float rstd = rsqrtf(s2 * (1.0f / 1024.0f) - mu * mu + 1e-5f);
  float4 gv = *(const float4*)(gam + t * 4);
  float4 bb = *(const float4*)(bet + t * 4);
  bf16x4 o;
  o[0] = (bf16)((v.x - mu) * rstd * gv.x + bb.x);
  o[1] = (bf16)((v.y - mu) * rstd * gv.y + bb.y);
  o[2] = (bf16)((v.z - mu) * rstd * gv.z + bb.z);
  o[3] = (bf16)((v.w - mu) * rstd * gv.w + bb.w);
  *(bf16x4*)(h2 + base) = o;
}

// ---------------- FFN2 combine: out = sum_z P_z + b2 + x2 ----------------
__global__ __launch_bounds__(256) void combine_ffn2(
    const bf16* __restrict__ P, const float* __restrict__ b2,
    const float* __restrict__ x2, float* __restrict__ out)
{
  const size_t i = ((size_t)blockIdx.x * 256 + threadIdx.x) * 4;
  const int col = (int)(i & 1023);
  float4 acc = *(const float4*)(x2 + i);
  float4 bv = *(const float4*)(b2 + col);
  acc.x += bv.x; acc.y += bv.y; acc.z += bv.z; acc.w += bv.w;
  #pragma unroll
  for (int z = 0; z < 4; ++z) {
    bf16x4 p = *(const bf16x4*)(P + (size_t)z * 4194304 + i);
    acc.x += (float)p[0]; acc.y += (float)p[1];
    acc.z += (float)p[2]; acc.w += (float)p[3];
  }
  *(float4*)(out + i) = acc;
}

// ---------------- flash attention (causal), constant-shift softmax ----------------
// R9: double-buffered K/V staging. Next chunk's global loads -> registers
// BEFORE compute, LDS writes AFTER compute, one barrier per chunk.
__global__ __launch_bounds__(256, 2) void attn_kernel(
    const bf16* __restrict__ qkv, const bf16* __restrict__ VtG,
    bf16* __restrict__ attnb)
{
  __shared__ bf16 Ks[2][64 * 72];
  __shared__ bf16 Vt[2][64 * 72];
  const int t = threadIdx.x, lane = t & 63, wv = t >> 6;
  const int li = lane & 15, g = lane >> 4;
  const int p = blockIdx.x & 15, h = (blockIdx.x >> 4) & 15, b = blockIdx.x >> 8;
  const int row0 = b << 11;
  const int tlo = p * 4 + wv, thi = 127 - tlo;
  const int q0l = tlo << 4, q0h = thi << 4;
  const size_t qkvbase = (size_t)row0 * 3072 + (size_t)h * 64;
  const bf16* vgbase = VtG + (size_t)(b * 16 + h) * 64 * 2048;

  const bf16* qpl = qkv + qkvbase + (size_t)(q0l + li) * 3072 + g * 8;
  const bf16* qph = qkv + qkvbase + (size_t)(q0h + li) * 3072 + g * 8;
  bf16x8 bl0 = *(const bf16x8*)(qpl), bl1 = *(const bf16x8*)(qpl + 32);
  bf16x8 bh0 = *(const bf16x8*)(qph), bh1 = *(const bf16x8*)(qph + 32);

  floatx4 ol[4] = {}, oh[4] = {};
  float ll = 0.f, lh = 0.f;
  const int cmax = 31 - p;

  // staging geometry (constant across chunks)
  const int krow0 = t >> 3, kdc = (t & 7) * 8;        // K rows: krow0, krow0+32
  const int vd = t >> 2, vkg = (t & 3) * 16;          // V: dim vd, keys vkg..+15
  bf16x8 kv0, kv1, vv0, vv1;                          // staging registers

  auto ld = [&](int c) {
    const size_t kb = qkvbase + (size_t)(c * 64) * 3072 + 1024;
    kv0 = *(const bf16x8*)(qkv + kb + (size_t)krow0 * 3072 + kdc);
    kv1 = *(const bf16x8*)(qkv + kb + (size_t)(krow0 + 32) * 3072 + kdc);
    const bf16* vg = vgbase + (size_t)vd * 2048 + c * 64 + vkg;
    vv0 = *(const bf16x8*)(vg);
    vv1 = *(const bf16x8*)(vg + 8);
  };
  auto wr = [&](int buf) {
    *(bf16x8*)(Ks[buf] + krow0 * 72 + kdc)        = kv0;
    *(bf16x8*)(Ks[buf] + (krow0 + 32) * 72 + kdc) = kv1;
    *(bf16x8*)(Vt[buf] + vd * 72 + vkg)           = vv0;
    *(bf16x8*)(Vt[buf] + vd * 72 + vkg + 8)       = vv1;
  };

  auto proc = [&](const bf16* KsB, const bf16* VtB,
                  const bf16x8& bq0, const bf16x8& bq1, float& l_i,
                  floatx4 (&o)[4], int qg, int k0, bool diag) {
    floatx4 sv[4];
    #pragma unroll
    for (int s = 0; s < 4; ++s) {
      const bf16* kr = KsB + (s * 16 + li) * 72 + g * 8;
      bf16x8 a0 = *(const bf16x8*)(kr);
      bf16x8 a1 = *(const bf16x8*)(kr + 32);
      floatx4 z = {0.f, 0.f, 0.f, 0.f};
      z = __builtin_amdgcn_mfma_f32_16x16x32_bf16(a0, bq0, z, 0, 0, 0);
      z = __builtin_amdgcn_mfma_f32_16x16x32_bf16(a1, bq1, z, 0, 0, 0);
      sv[s] = z;
    }
    float pv[4][4];
    float rs = 0.f;
    #pragma unroll
    for (int s = 0; s < 4; ++s)
      #pragma unroll
      for (int e = 0; e < 4; ++e) {
        float val = __expf(sv[s][e] * 0.125f - 4.0f);
        if (diag) {
          int kg = k0 + s * 16 + g * 4 + e;
          val = (kg <= qg) ? val : 0.0f;
        }
        pv[s][e] = val;
        rs += val;
      }
    rs += __shfl_xor(rs, 16);
    rs += __shfl_xor(rs, 32);
    l_i += rs;
    #pragma unroll
    for (int s = 0; s < 4; ++s) {
      shortx4 bp = { f2bf_bits(pv[s][0]), f2bf_bits(pv[s][1]),
                     f2bf_bits(pv[s][2]), f2bf_bits(pv[s][3]) };
      #pragma unroll
      for (int c = 0; c < 4; ++c) {
        shortx4 av = *(const shortx4*)(VtB + (c * 16 + li) * 72 + s * 16 + g * 4);
        o[c] = __builtin_amdgcn_mfma_f32_16x16x16bf16_1k(av, bp, o[c], 0, 0, 0);
      }
    }
  };

  ld(0);
  wr(0);
  __syncthreads();
  int buf = 0;
  for (int c = 0; c <= cmax; ++c) {
    if (c < cmax) ld(c + 1);                     // loads fly during compute
    proc(Ks[buf], Vt[buf], bh0, bh1, lh, oh, q0h + li, c * 64, c == cmax);
    if (c <= p) proc(Ks[buf], Vt[buf], bl0, bl1, ll, ol, q0l + li, c * 64, c == p);
    if (c < cmax) wr(buf ^ 1);                   // by now loads have landed
    __syncthreads();
    buf ^= 1;
  }

  const float invh = 1.0f / lh, invl = 1.0f / ll;
  #pragma unroll
  for (int c = 0; c < 4; ++c) {
    bf16x4 ovh = { (bf16)(oh[c][0] * invh), (bf16)(oh[c][1] * invh),
                   (bf16)(oh[c][2] * invh), (bf16)(oh[c][3] * invh) };
    *(bf16x4*)(attnb + (size_t)(row0 + q0h + li) * 1024 + h * 64 + c * 16 + g * 4) = ovh;
    bf16x4 ovl = { (bf16)(ol[c][0] * invl), (bf16)(ol[c][1] * invl),
                   (bf16)(ol[c][2] * invl), (bf16)(ol[c][3] * invl) };
    *(bf16x4*)(attnb + (size_t)(row0 + q0l + li) * 1024 + h * 64 + c * 16 + g * 4) = ovl;
  }
}

// ---------------- launch ----------------
extern "C" void kernel_launch(void* const* d_in, const int* in_sizes, int n_in,
                              void* d_out, int out_size, void* d_ws, size_t ws_size,
                              hipStream_t stream) {
  (void)in_sizes; (void)n_in; (void)out_size; (void)ws_size;
  const float* x    = (const float*)d_in[0];
  const float* Wq   = (const float*)d_in[1];
  const float* Wk   = (const float*)d_in[2];
  const float* Wv   = (const float*)d_in[3];
  const float* Wo   = (const float*)d_in[4];
  const float* bo   = (const float*)d_in[5];
  const float* W1   = (const float*)d_in[6];
  const float* b1   = (const float*)d_in[7];
  const float* W2   = (const float*)d_in[8];
  const float* b2   = (const float*)d_in[9];
  const float* ln1g = (const float*)d_in[10];
  const float* ln1b = (const float*)d_in[11];
  const float* ln2g = (const float*)d_in[12];
  const float* ln2b = (const float*)d_in[13];
  float* out = (float*)d_out;
  char* ws = (char*)d_ws;

  constexpr size_t OFF_WQKVT = 0;
  constexpr size_t OFF_WOT   = OFF_WQKVT + 3072ull * 1024 * 2;
  constexpr size_t OFF_W1T   = OFF_WOT   + 1024ull * 1024 * 2;
  constexpr size_t OFF_W2T   = OFF_W1T   + 4096ull * 1024 * 2;
  constexpr size_t OFF_H1    = OFF_W2T   + 1024ull * 4096 * 2;
  constexpr size_t OFF_QKV   = OFF_H1    + 4096ull * 1024 * 2;
  constexpr size_t OFF_ATT   = OFF_QKV   + 4096ull * 3072 * 2;
  constexpr size_t OFF_X2    = OFF_ATT   + 4096ull * 1024 * 2;
  constexpr size_t OFF_H2    = OFF_X2    + 4096ull * 1024 * 4;
  constexpr size_t OFF_F1    = OFF_H2    + 4096ull * 1024 * 2;
  constexpr size_t OFF_PART  = OFF_F1    + 4096ull * 4096 * 2;      // 4x [4096,1024] bf16
  constexpr size_t OFF_VTG   = OFF_PART  + 4ull * 4096 * 1024 * 2;  // [32][64][2048] bf16

  bf16*  WqkvT = (bf16*)(ws + OFF_WQKVT);
  bf16*  WoT   = (bf16*)(ws + OFF_WOT);
  bf16*  W1T   = (bf16*)(ws + OFF_W1T);
  bf16*  W2T   = (bf16*)(ws + OFF_W2T);
  bf16*  h1    = (bf16*)(ws + OFF_H1);
  bf16*  qkv   = (bf16*)(ws + OFF_QKV);
  bf16*  attnb = (bf16*)(ws + OFF_ATT);
  float* x2    = (float*)(ws + OFF_X2);
  bf16*  h2    = (bf16*)(ws + OFF_H2);
  bf16*  f1    = (bf16*)(ws + OFF_F1);
  bf16*  part  = (bf16*)(ws + OFF_PART);
  bf16*  vtg   = (bf16*)(ws + OFF_VTG);

  prep_kernel<<<16384, 256, 0, stream>>>(Wq, Wk, Wv, Wo, W1, W2,
                                         WqkvT, WoT, W1T, W2T, x, ln1g, ln1b, h1);
  gemm_qkv<<<dim3(32, 24), 256, 0, stream>>>(h1, WqkvT, qkv, vtg);
  attn_kernel<<<512, 256, 0, stream>>>(qkv, vtg, attnb);
  gemm_splitk<<<dim3(32, 8, 2), 256, 0, stream>>>(attnb, WoT, part, 4096, 1024, 1024, 512);
  combine_wo_ln2<<<4096, 256, 0, stream>>>(part, bo, x, ln2g, ln2b, x2, h2);
  gemm_kernel<true, true, false><<<dim3(32, 32), 256, 0, stream>>>(
      h2, W1T, b1, nullptr, f1, nullptr, 4096, 4096, 1024);
  gemm_splitk<<<dim3(32, 8, 4), 256, 0, stream>>>(f1, W2T, part, 4096, 1024, 4096, 1024);
  combine_ffn2<<<4096, 256, 0, stream>>>(part, b2, x2, out);
}